// Round 2
// baseline (868.100 us; speedup 1.0000x reference)
//
#include <hip/hip_runtime.h>

#define N_NODES 100000
#define N_EDGES 1000000
#define D 64
#define N_TYPES 16
#define SCAN_THREADS 1024
#define SCAN_ITEMS 98           // 1024*98 = 100352 >= N_NODES
#define APPLY_BPT 48            // blocks per type in apply kernel

// ---------------- workspace layout (in 4-byte units) ----------------
// cnt   [N_NODES]        zeroed     edge histogram by dst
// tcnt  [N_TYPES]        zeroed     node histogram by type   (contiguous w/ cnt for one memset)
// off   [N_NODES+1]                 CSR offsets
// cur   [N_NODES]                   fill cursors (= off copy)
// toff  [N_TYPES+1]                 type offsets
// tcur  [N_TYPES]                   type cursors
// nlist [N_NODES]                   nodes grouped by type
// adj   [N_EDGES]                   src ids grouped by dst
#define WS_CNT    0
#define WS_TCNT   (WS_CNT + N_NODES)
#define WS_OFF    (WS_TCNT + N_TYPES)
#define WS_CUR    (WS_OFF + N_NODES + 1)
#define WS_TOFF   (WS_CUR + N_NODES)
#define WS_TCUR   (WS_TOFF + N_TYPES + 1)
#define WS_NLIST  (WS_TCUR + N_TYPES)
#define WS_ADJ    (WS_NLIST + N_NODES)
#define WS_TOTAL  (WS_ADJ + N_EDGES)

// ---- histogram: edges by dst ----
__global__ void hist_edges(const int* __restrict__ dst, int* __restrict__ cnt) {
    int e = blockIdx.x * blockDim.x + threadIdx.x;
    if (e >= N_EDGES) return;
    atomicAdd(cnt + dst[e], 1);
}

// ---- single-block scan: CSR offsets + type offsets ----
__global__ void __launch_bounds__(SCAN_THREADS)
scan_offsets(const int* __restrict__ cnt, int* __restrict__ off, int* __restrict__ cur,
             const int* __restrict__ tcnt, int* __restrict__ toff, int* __restrict__ tcur) {
    __shared__ int part[SCAN_THREADS];
    int t = threadIdx.x;
    int base_idx = t * SCAN_ITEMS;
    int s = 0;
    for (int j = 0; j < SCAN_ITEMS; ++j) {
        int idx = base_idx + j;
        if (idx < N_NODES) s += cnt[idx];
    }
    part[t] = s;
    __syncthreads();
    for (int o = 1; o < SCAN_THREADS; o <<= 1) {
        int v = (t >= o) ? part[t - o] : 0;
        __syncthreads();
        part[t] += v;
        __syncthreads();
    }
    int run = (t == 0) ? 0 : part[t - 1];
    for (int j = 0; j < SCAN_ITEMS; ++j) {
        int idx = base_idx + j;
        if (idx < N_NODES) {
            off[idx] = run;
            cur[idx] = run;
            run += cnt[idx];
        }
    }
    if (t == SCAN_THREADS - 1) off[N_NODES] = part[SCAN_THREADS - 1];
    if (t == 0) {
        int r = 0;
        for (int k = 0; k < N_TYPES; ++k) { toff[k] = r; tcur[k] = r; r += tcnt[k]; }
        toff[N_TYPES] = r;
    }
}

// ---- node-type histogram (16 counters; LDS pre-reduce to cut contention) ----
__global__ void hist_types(const int* __restrict__ ntype2, int* __restrict__ tcnt) {
    __shared__ int loc[N_TYPES];
    if (threadIdx.x < N_TYPES) loc[threadIdx.x] = 0;
    __syncthreads();
    int n = blockIdx.x * blockDim.x + threadIdx.x;
    if (n < N_NODES) atomicAdd(loc + ntype2[n], 1);
    __syncthreads();
    if (threadIdx.x < N_TYPES && loc[threadIdx.x]) atomicAdd(tcnt + threadIdx.x, loc[threadIdx.x]);
}

// ---- fill CSR adjacency + type-grouped node list ----
__global__ void fill_lists(const int* __restrict__ src, const int* __restrict__ dst,
                           const int* __restrict__ ntype2,
                           int* __restrict__ cur, int* __restrict__ adj,
                           int* __restrict__ tcur, int* __restrict__ nlist) {
    int tid = blockIdx.x * blockDim.x + threadIdx.x;
    if (tid < N_EDGES) {
        int d = dst[tid];
        int slot = atomicAdd(cur + d, 1);
        adj[slot] = src[tid];
    }
    if (tid < N_NODES) {
        int t = ntype2[tid];
        int slot = atomicAdd(tcur + t, 1);
        nlist[slot] = tid;
    }
}

// ---- gather + mean: one wave per node, lane = dim; no atomics ----
__global__ void gather_mean(const float* __restrict__ feat,
                            const int* __restrict__ off, const int* __restrict__ adj,
                            float* __restrict__ out) {
    int node = blockIdx.x * (blockDim.x >> 6) + (threadIdx.x >> 6);
    int lane = threadIdx.x & 63;
    if (node >= N_NODES) return;
    int beg = off[node], end = off[node + 1];
    float acc = 0.0f;
    for (int base = beg; base < end; base += 64) {
        int sl = (base + lane < end) ? adj[base + lane] : 0;
        int m = end - base; if (m > 64) m = 64;
        for (int j = 0; j < m; ++j) {
            int s = __shfl(sl, j, 64);
            acc += feat[s * D + lane];
        }
    }
    int deg = end - beg;
    float dv = (deg > 1) ? (float)deg : 1.0f;
    out[node * D + lane] = acc / dv;      // zero-degree rows -> 0
}

// ---- type-grouped linear: W cached in LDS, in-place over out ----
__global__ void __launch_bounds__(256)
apply_typed(const float* __restrict__ gate_W, const float* __restrict__ gate_b,
            const int* __restrict__ toff, const int* __restrict__ nlist,
            float* __restrict__ out) {
    __shared__ float Wl[D * D];
    int t = blockIdx.x / APPLY_BPT;
    int c = blockIdx.x % APPLY_BPT;
    const float* W = gate_W + t * D * D;
    for (int i = threadIdx.x; i < D * D; i += blockDim.x) Wl[i] = W[i];
    __syncthreads();

    int lane = threadIdx.x & 63;
    int wv = threadIdx.x >> 6;
    int beg = toff[t], cnt_t = toff[t + 1] - beg;
    float bias = gate_b[t * D + lane];

    for (int i = c * 4 + wv; i < cnt_t; i += APPLY_BPT * 4) {
        int node = nlist[beg + i];
        float nv = out[node * D + lane];
        float acc = bias;
#pragma unroll 16
        for (int d = 0; d < D; ++d) {
            float x = __shfl(nv, d, 64);
            acc = fmaf(x, Wl[d * D + lane], acc);
        }
        out[node * D + lane] = acc;
    }
}

// ================= fallback (round-1 atomic path) =================
__global__ void scatter_feat(const float* __restrict__ feat, const int* __restrict__ src,
                             const int* __restrict__ dst, float* __restrict__ accum) {
    long long idx = (long long)blockIdx.x * blockDim.x + threadIdx.x;
    if (idx >= (long long)N_EDGES * D) return;
    int e = (int)(idx >> 6), d = (int)(idx & 63);
    atomicAdd(accum + dst[e] * D + d, feat[src[e] * D + d]);
}
__global__ void scatter_deg(const int* __restrict__ dst, float* __restrict__ deg) {
    int e = blockIdx.x * blockDim.x + threadIdx.x;
    if (e >= N_EDGES) return;
    atomicAdd(deg + dst[e], 1.0f);
}
__global__ void apply_linear(const float* __restrict__ gate_W, const float* __restrict__ gate_b,
                             const int* __restrict__ ntype2, const float* __restrict__ deg,
                             float* __restrict__ out) {
    int node = blockIdx.x * (blockDim.x >> 6) + (threadIdx.x >> 6);
    int lane = threadIdx.x & 63;
    if (node >= N_NODES) return;
    int t = ntype2[node];
    float dv = deg[node]; dv = dv > 1.0f ? dv : 1.0f;
    float nv = out[node * D + lane] / dv;
    const float* W = gate_W + t * D * D;
    float acc = gate_b[t * D + lane];
#pragma unroll 16
    for (int d = 0; d < D; ++d)
        acc = fmaf(__shfl(nv, d, 64), W[d * D + lane], acc);
    out[node * D + lane] = acc;
}
// ==================================================================

extern "C" void kernel_launch(void* const* d_in, const int* in_sizes, int n_in,
                              void* d_out, int out_size, void* d_ws, size_t ws_size,
                              hipStream_t stream) {
    const float* feat   = (const float*)d_in[0];
    const float* gate_W = (const float*)d_in[1];
    const float* gate_b = (const float*)d_in[2];
    const int*   src    = (const int*)d_in[3];
    const int*   dst    = (const int*)d_in[4];
    const int*   ntype2 = (const int*)d_in[5];
    float* out = (float*)d_out;

    if (ws_size >= (size_t)WS_TOTAL * 4) {
        int* ws = (int*)d_ws;
        int* cnt   = ws + WS_CNT;
        int* tcnt  = ws + WS_TCNT;
        int* off   = ws + WS_OFF;
        int* cur   = ws + WS_CUR;
        int* toff  = ws + WS_TOFF;
        int* tcur  = ws + WS_TCUR;
        int* nlist = ws + WS_NLIST;
        int* adj   = ws + WS_ADJ;

        // zero cnt + tcnt (contiguous)
        hipMemsetAsync(cnt, 0, sizeof(int) * (N_NODES + N_TYPES), stream);

        hist_edges<<<(N_EDGES + 255) / 256, 256, 0, stream>>>(dst, cnt);
        hist_types<<<(N_NODES + 255) / 256, 256, 0, stream>>>(ntype2, tcnt);
        scan_offsets<<<1, SCAN_THREADS, 0, stream>>>(cnt, off, cur, tcnt, toff, tcur);
        fill_lists<<<(N_EDGES + 255) / 256, 256, 0, stream>>>(src, dst, ntype2, cur, adj, tcur, nlist);
        gather_mean<<<(N_NODES + 3) / 4, 256, 0, stream>>>(feat, off, adj, out);
        apply_typed<<<N_TYPES * APPLY_BPT, 256, 0, stream>>>(gate_W, gate_b, toff, nlist, out);
    } else {
        // fallback: atomic scatter path
        float* deg = (float*)d_ws;
        hipMemsetAsync(out, 0, sizeof(float) * N_NODES * D, stream);
        hipMemsetAsync(deg, 0, sizeof(float) * N_NODES, stream);
        long long total = (long long)N_EDGES * D;
        scatter_feat<<<(int)((total + 255) / 256), 256, 0, stream>>>(feat, src, dst, out);
        scatter_deg<<<(N_EDGES + 255) / 256, 256, 0, stream>>>(dst, deg);
        apply_linear<<<(N_NODES + 3) / 4, 256, 0, stream>>>(gate_W, gate_b, ntype2, deg, out);
    }
}

// Round 3
// 588.705 us; speedup vs baseline: 1.4746x; 1.4746x over previous
//
#include <hip/hip_runtime.h>

#define N_NODES 100000
#define N_EDGES 1000000
#define D 64
#define N_TYPES 16

#define NPB 128                                  // nodes per bucket (dst >> 7)
#define NBUCK ((N_NODES + NPB - 1) / NPB)        // 782
#define NBLK 256                                 // edge chunks / blocks in sort
#define CHUNK ((N_EDGES + NBLK - 1) / NBLK)      // 3907

// ---------------- workspace layout (4-byte units) ----------------
// tbl    [NBUCK*NBLK]   per-(bucket,block) counts -> exclusive prefixes
// btot   [NBUCK]        per-bucket totals
// bstart [NBUCK+1]      bucket start offsets in ebuf
// ebuf   [N_EDGES]      packed (dstLocal<<20 | src)
#define WS_TBL    0
#define WS_BTOT   (WS_TBL + NBUCK * NBLK)
#define WS_BSTART (WS_BTOT + NBUCK)
#define WS_EBUF   (WS_BSTART + NBUCK + 1)
#define WS_TOTAL  (WS_EBUF + N_EDGES)

// ---- A1: per-chunk LDS histogram over buckets; plain stores to table ----
__global__ void __launch_bounds__(512)
hist_chunks(const int* __restrict__ dst, int* __restrict__ tbl) {
    __shared__ int h[NBUCK];
    for (int i = threadIdx.x; i < NBUCK; i += 512) h[i] = 0;
    __syncthreads();
    int b = blockIdx.x;
    int beg = b * CHUNK, end = min(beg + CHUNK, N_EDGES);
    for (int e = beg + (int)threadIdx.x; e < end; e += 512)
        atomicAdd(&h[dst[e] >> 7], 1);
    __syncthreads();
    for (int i = threadIdx.x; i < NBUCK; i += 512) tbl[i * NBLK + b] = h[i];
}

// ---- A2a: wave-per-bucket exclusive scan of the 256 block counts ----
__global__ void __launch_bounds__(512)
scan_cols(int* __restrict__ tbl, int* __restrict__ btot) {
    int wave = blockIdx.x * 8 + (threadIdx.x >> 6);
    int lane = threadIdx.x & 63;
    if (wave >= NBUCK) return;
    int4 v = ((int4*)(tbl + wave * NBLK))[lane];
    int s01 = v.x + v.y;
    int s = s01 + v.z + v.w;
    int incl = s;
    for (int o = 1; o < 64; o <<= 1) {
        int u = __shfl_up(incl, o, 64);
        if (lane >= o) incl += u;
    }
    int excl = incl - s;
    int4 w;
    w.x = excl; w.y = excl + v.x; w.z = excl + s01; w.w = excl + s01 + v.z;
    ((int4*)(tbl + wave * NBLK))[lane] = w;
    if (lane == 63) btot[wave] = incl;           // column total
}

// ---- A2b: single-block scan of bucket totals -> bucket starts ----
__global__ void __launch_bounds__(1024)
scan_buckets(const int* __restrict__ btot, int* __restrict__ bstart) {
    __shared__ int sh[1024];
    int t = threadIdx.x;
    int v = (t < NBUCK) ? btot[t] : 0;
    sh[t] = v;
    __syncthreads();
    for (int o = 1; o < 1024; o <<= 1) {
        int u = (t >= o) ? sh[t - o] : 0;
        __syncthreads();
        sh[t] += u;
        __syncthreads();
    }
    if (t <= NBUCK) bstart[t] = sh[t] - v;       // exclusive; t==NBUCK -> total
}

// ---- A3: place edges via LDS cursors; plain semi-contiguous stores ----
__global__ void __launch_bounds__(512)
place_edges(const int* __restrict__ src, const int* __restrict__ dst,
            const int* __restrict__ tbl, const int* __restrict__ bstart,
            unsigned* __restrict__ ebuf) {
    __shared__ int cur[NBUCK];
    int b = blockIdx.x;
    for (int i = threadIdx.x; i < NBUCK; i += 512)
        cur[i] = bstart[i] + tbl[i * NBLK + b];
    __syncthreads();
    int beg = b * CHUNK, end = min(beg + CHUNK, N_EDGES);
    for (int e = beg + (int)threadIdx.x; e < end; e += 512) {
        int d = dst[e];
        int slot = atomicAdd(&cur[d >> 7], 1);   // LDS atomic only
        ebuf[slot] = ((unsigned)(d & (NPB - 1)) << 20) | (unsigned)src[e];
    }
}

// ---- B: per-bucket LDS segment-sum + mean + fused type-routed linear ----
__global__ void __launch_bounds__(512)
bucket_conv(const float* __restrict__ feat,
            const float* __restrict__ gate_W,
            const float* __restrict__ gate_b,
            const int* __restrict__ ntype2,
            const int* __restrict__ bstart,
            const unsigned* __restrict__ ebuf,
            float* __restrict__ out) {
    __shared__ float acc[NPB * D];               // 32 KB
    __shared__ float degL[NPB];
    __shared__ int tc[N_TYPES];
    __shared__ unsigned char tl[N_TYPES][NPB];

    int k = blockIdx.x;
    int tid = threadIdx.x;
    int lane = tid & 63;
    int wave = tid >> 6;                         // 0..7

    for (int i = tid; i < NPB * D; i += 512) acc[i] = 0.0f;
    if (tid < NPB) degL[tid] = 0.0f;
    if (tid < N_TYPES) tc[tid] = 0;
    __syncthreads();

    int beg = bstart[k], end = bstart[k + 1];
    for (int base = beg + wave * 64; base < end; base += 8 * 64) {
        unsigned e = (base + lane < end) ? ebuf[base + lane] : 0u;
        int m = end - base; if (m > 64) m = 64;
#pragma unroll 4
        for (int j = 0; j < m; ++j) {
            unsigned p = __shfl(e, j, 64);
            int dl = (int)(p >> 20);
            int s  = (int)(p & 0xFFFFFu);
            float v = feat[s * D + lane];        // coalesced 256B row
            atomicAdd(&acc[dl * D + lane], v);   // ds_add_f32, no return
            if (lane == 0) atomicAdd(&degL[dl], 1.0f);
        }
    }
    __syncthreads();

    // scale by 1/max(deg,1)
    for (int i = tid; i < NPB * D; i += 512) {
        float dv = degL[i >> 6];
        acc[i] *= (dv > 1.0f) ? (1.0f / dv) : 1.0f;
    }
    // per-type node lists (LDS atomics)
    int node0 = k * NPB;
    if (tid < NPB && node0 + tid < N_NODES) {
        int t = ntype2[node0 + tid];
        int pos = atomicAdd(&tc[t], 1);
        tl[t][pos] = (unsigned char)tid;
    }
    __syncthreads();

    // all waves march types together -> W[t] stays L1-hot
    for (int t = 0; t < N_TYPES; ++t) {
        int cnt = tc[t];
        if (cnt == 0) continue;
        const float* __restrict__ W = gate_W + t * D * D;
        float bias = gate_b[t * D + lane];
        for (int i = wave; i < cnt; i += 8) {
            int n = tl[t][i];
            float a = bias;
#pragma unroll 16
            for (int d = 0; d < D; ++d)
                a = fmaf(acc[n * D + d], W[d * D + lane], a);  // LDS broadcast * coalesced W
            out[(node0 + n) * D + lane] = a;
        }
    }
}

// ================= fallback (round-1 atomic path) =================
__global__ void scatter_feat(const float* __restrict__ feat, const int* __restrict__ src,
                             const int* __restrict__ dst, float* __restrict__ accum) {
    long long idx = (long long)blockIdx.x * blockDim.x + threadIdx.x;
    if (idx >= (long long)N_EDGES * D) return;
    int e = (int)(idx >> 6), d = (int)(idx & 63);
    atomicAdd(accum + dst[e] * D + d, feat[src[e] * D + d]);
}
__global__ void scatter_deg(const int* __restrict__ dst, float* __restrict__ deg) {
    int e = blockIdx.x * blockDim.x + threadIdx.x;
    if (e >= N_EDGES) return;
    atomicAdd(deg + dst[e], 1.0f);
}
__global__ void apply_linear(const float* __restrict__ gate_W, const float* __restrict__ gate_b,
                             const int* __restrict__ ntype2, const float* __restrict__ deg,
                             float* __restrict__ out) {
    int node = blockIdx.x * (blockDim.x >> 6) + (threadIdx.x >> 6);
    int lane = threadIdx.x & 63;
    if (node >= N_NODES) return;
    int t = ntype2[node];
    float dv = deg[node]; dv = dv > 1.0f ? dv : 1.0f;
    float nv = out[node * D + lane] / dv;
    const float* W = gate_W + t * D * D;
    float acc = gate_b[t * D + lane];
#pragma unroll 16
    for (int d = 0; d < D; ++d)
        acc = fmaf(__shfl(nv, d, 64), W[d * D + lane], acc);
    out[node * D + lane] = acc;
}
// ==================================================================

extern "C" void kernel_launch(void* const* d_in, const int* in_sizes, int n_in,
                              void* d_out, int out_size, void* d_ws, size_t ws_size,
                              hipStream_t stream) {
    const float* feat   = (const float*)d_in[0];
    const float* gate_W = (const float*)d_in[1];
    const float* gate_b = (const float*)d_in[2];
    const int*   src    = (const int*)d_in[3];
    const int*   dst    = (const int*)d_in[4];
    const int*   ntype2 = (const int*)d_in[5];
    float* out = (float*)d_out;

    if (ws_size >= (size_t)WS_TOTAL * 4) {
        int* ws = (int*)d_ws;
        int* tbl      = ws + WS_TBL;
        int* btot     = ws + WS_BTOT;
        int* bstart   = ws + WS_BSTART;
        unsigned* ebuf = (unsigned*)(ws + WS_EBUF);

        hist_chunks<<<NBLK, 512, 0, stream>>>(dst, tbl);
        scan_cols<<<(NBUCK + 7) / 8, 512, 0, stream>>>(tbl, btot);
        scan_buckets<<<1, 1024, 0, stream>>>(btot, bstart);
        place_edges<<<NBLK, 512, 0, stream>>>(src, dst, tbl, bstart, ebuf);
        bucket_conv<<<NBUCK, 512, 0, stream>>>(feat, gate_W, gate_b, ntype2,
                                               bstart, ebuf, out);
    } else {
        float* deg = (float*)d_ws;
        hipMemsetAsync(out, 0, sizeof(float) * N_NODES * D, stream);
        hipMemsetAsync(deg, 0, sizeof(float) * N_NODES, stream);
        long long total = (long long)N_EDGES * D;
        scatter_feat<<<(int)((total + 255) / 256), 256, 0, stream>>>(feat, src, dst, out);
        scatter_deg<<<(N_EDGES + 255) / 256, 256, 0, stream>>>(dst, deg);
        apply_linear<<<(N_NODES + 3) / 4, 256, 0, stream>>>(gate_W, gate_b, ntype2, deg, out);
    }
}